// Round 3
// baseline (1855.357 us; speedup 1.0000x reference)
//
#include <hip/hip_runtime.h>
#include <hip/hip_bf16.h>
#include <stdint.h>

#define NL 4
#define DM 512
#define DI 1024
#define DS 16
#define DTR 32
#define DCONV 4
#define BB 2
#define LTOT 1024
#define NCC 768
#define NTT 256
#define EPSV 1e-5f
#define NIN 13

typedef __hip_bfloat16 bf16;
__device__ __forceinline__ float b2f(bf16 v){ return __bfloat162float(v); }

struct ConvArgs { const void* src[NIN]; int prefix[NIN+1]; };

// ---------------- dtype detector: flag=1 if buffers are f32, 0 if bf16 ----------------
__global__ void k_detect(const unsigned short* __restrict__ u, int* __restrict__ flag){
  __shared__ int cnt[2];
  if (threadIdx.x < 2) cnt[threadIdx.x] = 0;
  __syncthreads();
  int h = 0, z = 0;
  for (int i = threadIdx.x; i < 4096; i += 256){
    unsigned short b = u[2*i];
    if (b == 0) z++;
    int e = (b >> 7) & 0xFF;
    if (e >= 142 && e != 0xFF) h++;
  }
  atomicAdd(&cnt[0], h);
  atomicAdd(&cnt[1], z);
  __syncthreads();
  if (threadIdx.x == 0) *flag = (cnt[0] > 64 || cnt[1] > 64) ? 1 : 0;
}

// ---------------- stage all inputs as f32 ----------------
__global__ __launch_bounds__(256) void k_convert(ConvArgs a, float* __restrict__ dst,
                                                 const int* __restrict__ flag, int total){
  int idx = blockIdx.x*256 + threadIdx.x;
  if (idx >= total) return;
  int bi = 0;
  #pragma unroll
  for (int i = 0; i < NIN-1; ++i) if (idx >= a.prefix[i+1]) bi = i+1;
  int off = idx - a.prefix[bi];
  float v = (*flag) ? ((const float*)a.src[bi])[off]
                    : b2f(((const bf16*)a.src[bi])[off]);
  dst[idx] = v;
}

// ---------------- init: concat xc|xt -> X (f32) ----------------
__global__ void k_init(const float* __restrict__ xc, const float* __restrict__ xt, float* __restrict__ X){
  int idx = blockIdx.x*256 + threadIdx.x;
  if (idx >= BB*LTOT*DM) return;
  int c = idx & (DM-1);
  int row = idx >> 9;
  int t = row & (LTOT-1);
  int b = row >> 10;
  X[idx] = (t < NCC) ? xc[(b*NCC + t)*DM + c] : xt[(b*NTT + (t-NCC))*DM + c];
}

// ---------------- layernorm over DM=512 ----------------
__global__ __launch_bounds__(256) void k_ln(const float* __restrict__ X, const float* __restrict__ w,
                                            const float* __restrict__ bia, float* __restrict__ LN){
  __shared__ float red[4];
  int row = blockIdx.x, tid = threadIdx.x;
  const float* xr = X + row*DM;
  float v0 = xr[tid], v1 = xr[tid+256];
  float s = v0 + v1;
  #pragma unroll
  for (int m = 32; m >= 1; m >>= 1) s += __shfl_xor(s, m, 64);
  if ((tid & 63) == 0) red[tid>>6] = s;
  __syncthreads();
  float mean = (red[0]+red[1]+red[2]+red[3]) * (1.0f/DM);
  __syncthreads();
  float d0 = v0-mean, d1 = v1-mean;
  float q = d0*d0 + d1*d1;
  #pragma unroll
  for (int m = 32; m >= 1; m >>= 1) q += __shfl_xor(q, m, 64);
  if ((tid & 63) == 0) red[tid>>6] = q;
  __syncthreads();
  float var = (red[0]+red[1]+red[2]+red[3]) * (1.0f/DM);
  float rs = rsqrtf(var + EPSV);
  LN[row*DM + tid]     = d0*rs*w[tid]     + bia[tid];
  LN[row*DM + tid+256] = d1*rs*w[tid+256] + bia[tid+256];
}

// ---------------- tiled f32 GEMM: C[M,N] (=|+=) A[M,K] @ W[K,N] ----------------
template<int ACC>
__global__ __launch_bounds__(256) void k_gemm64(const float* __restrict__ A, const float* __restrict__ W,
                                                float* __restrict__ C, int M, int N, int K){
  __shared__ __align__(16) float As[16][68];
  __shared__ __align__(16) float Ws[16][64];
  int tid = threadIdx.x;
  int tx = tid & 15, ty = tid >> 4;
  int n0 = blockIdx.x * 64, m0 = blockIdx.y * 64;
  int la_k = tid & 15, la_m = tid >> 4;
  int lw_n = tid & 63, lw_k = tid >> 6;
  float acc[4][4] = {};
  for (int k0 = 0; k0 < K; k0 += 16){
    #pragma unroll
    for (int e=0;e<4;e++)
      As[la_k][la_m + e*16] = A[(m0 + la_m + e*16)*K + k0 + la_k];
    #pragma unroll
    for (int e=0;e<4;e++)
      Ws[lw_k + e*4][lw_n] = W[(k0 + lw_k + e*4)*N + n0 + lw_n];
    __syncthreads();
    #pragma unroll
    for (int kk=0; kk<16; ++kk){
      float4 av = *(const float4*)&As[kk][ty*4];
      float4 bv = *(const float4*)&Ws[kk][tx*4];
      float a[4] = {av.x, av.y, av.z, av.w};
      float b[4] = {bv.x, bv.y, bv.z, bv.w};
      #pragma unroll
      for (int i=0;i<4;i++)
        #pragma unroll
        for (int j=0;j<4;j++)
          acc[i][j] = fmaf(a[i], b[j], acc[i][j]);
    }
    __syncthreads();
  }
  #pragma unroll
  for (int i=0;i<4;i++){
    int m = m0 + ty*4 + i;
    #pragma unroll
    for (int j=0;j<4;j++){
      int n = n0 + tx*4 + j;
      if (ACC) C[m*N+n] += acc[i][j];
      else     C[m*N+n]  = acc[i][j];
    }
  }
}

// ---------------- causal depthwise conv (D_CONV=4) + bias + SiLU ----------------
__global__ void k_conv(const float* __restrict__ XZ, const float* __restrict__ cw,
                       const float* __restrict__ cb, float* __restrict__ XC){
  int idx = blockIdx.x*256 + threadIdx.x;
  if (idx >= BB*LTOT*DI) return;
  int d = idx & (DI-1);
  int row = idx >> 10;
  int t = row & (LTOT-1);
  float acc = cb[d];
  #pragma unroll
  for (int k=0;k<DCONV;k++){
    int tt = t + k - (DCONV-1);
    if (tt >= 0) acc = fmaf(XZ[(row + k - (DCONV-1))*2*DI + d], cw[d*DCONV+k], acc);
  }
  acc = acc / (1.f + __expf(-acc));
  XC[idx] = acc;
}

// ---------------- DBL[M,64] = XC[M,1024] @ Wx[1024,64] ----------------
__global__ __launch_bounds__(256) void k_dbl(const float* __restrict__ XC, const float* __restrict__ Wx,
                                             float* __restrict__ DBL){
  __shared__ float sx[4][DI];
  int tid = threadIdx.x;
  int m0 = blockIdx.x * 4;
  #pragma unroll
  for (int e = 0; e < 16; ++e){
    int off = e*256 + tid;
    sx[off >> 10][off & (DI-1)] = XC[(m0 + (off>>10))*DI + (off & (DI-1))];
  }
  __syncthreads();
  int r = tid >> 6, c = tid & 63;
  float acc = 0.f;
  #pragma unroll 8
  for (int k=0;k<DI;k++) acc = fmaf(sx[r][k], Wx[k*64 + c], acc);
  DBL[(m0+r)*64 + c] = acc;
}

// ---------------- DELTA[M,1024] = softplus(DBL[:, :32] @ Wdt[32,1024] + b_dt) ----------------
__global__ __launch_bounds__(256) void k_delta(const float* __restrict__ DBL, const float* __restrict__ Wdt,
                                               const float* __restrict__ bdt, float* __restrict__ DELTA){
  __shared__ float sdt[DTR];
  int m = blockIdx.y;
  int n0 = blockIdx.x*256;
  int tid = threadIdx.x;
  if (tid < DTR) sdt[tid] = DBL[m*64 + tid];
  __syncthreads();
  int n = n0 + tid;
  float acc = bdt[n];
  #pragma unroll
  for (int k=0;k<DTR;k++) acc = fmaf(sdt[k], Wdt[k*DI + n], acc);
  DELTA[m*DI + n] = (acc > 20.f) ? acc : log1pf(__expf(acc));
}

// ---------------- selective scan + fused epilogue: Y = (scan + x*D) * silu(z) ----------------
__global__ __launch_bounds__(256) void k_scan(const float* __restrict__ DELTA, const float* __restrict__ XC,
                                              const float* __restrict__ XZ, const float* __restrict__ DBL,
                                              const float* __restrict__ Alog, const float* __restrict__ Dv,
                                              float* __restrict__ Y){
  __shared__ float s_del[64][16], s_x[64][16], s_z[64][16], s_B[64][16], s_C[64][16], s_y[64][16];
  int tid = threadIdx.x;
  int ch = tid >> 4, n = tid & 15;
  int g0 = blockIdx.x * 16;
  int b  = g0 >> 10;
  int d0 = g0 & (DI-1);
  int d  = d0 + ch;
  float An = -__expf(Alog[d*DS + n]);
  float Dd = Dv[d];
  float h = 0.f;
  int lj = tid & 15, li = tid >> 4;
  for (int t0 = 0; t0 < LTOT; t0 += 64){
    #pragma unroll
    for (int e=0;e<4;e++){
      int i = li + e*16;
      int row = b*LTOT + t0 + i;
      s_del[i][lj] = DELTA[row*DI + d0 + lj];
      s_x[i][lj]   = XC[row*DI + d0 + lj];
      s_z[i][lj]   = XZ[row*2*DI + DI + d0 + lj];
      s_B[i][lj]   = DBL[row*64 + 32 + lj];
      s_C[i][lj]   = DBL[row*64 + 48 + lj];
    }
    __syncthreads();
    for (int t=0;t<64;t++){
      float del = s_del[t][ch];
      float xv  = s_x[t][ch];
      float dA  = __expf(del * An);
      h = fmaf(dA, h, del * s_B[t][n] * xv);
      float p = h * s_C[t][n];
      p += __shfl_xor(p, 8, 16);
      p += __shfl_xor(p, 4, 16);
      p += __shfl_xor(p, 2, 16);
      p += __shfl_xor(p, 1, 16);
      if (n == 0){
        float z = s_z[t][ch];
        s_y[t][ch] = (p + xv * Dd) * (z / (1.f + __expf(-z)));
      }
    }
    __syncthreads();
    #pragma unroll
    for (int e=0;e<4;e++){
      int i = li + e*16;
      int row = b*LTOT + t0 + i;
      Y[row*DI + d0 + lj] = s_y[i][lj];
    }
    __syncthreads();
  }
}

// ---------------- final slice + dtype-dispatched store ----------------
__global__ void k_out(const float* __restrict__ X, void* __restrict__ out, const int* __restrict__ flag){
  int idx = blockIdx.x*256 + threadIdx.x;
  if (idx >= BB*NTT*DM) return;
  int c = idx & (DM-1);
  int r = idx >> 9;
  int t = r & (NTT-1);
  int b = r >> 8;
  float v = X[(b*LTOT + NCC + t)*DM + c];
  if (*flag) ((float*)out)[idx] = v;
  else       ((bf16*)out)[idx] = __float2bfloat16(v);
}

extern "C" void kernel_launch(void* const* d_in, const int* in_sizes, int n_in,
                              void* d_out, int out_size, void* d_ws, size_t ws_size,
                              hipStream_t stream){
  ConvArgs a;
  int total = 0;
  for (int i = 0; i < NIN; ++i){ a.src[i] = d_in[i]; a.prefix[i] = total; total += in_sizes[i]; }
  a.prefix[NIN] = total;

  float* ws = (float*)d_ws;
  int* flag = (int*)d_ws;
  size_t o = 16;                       // floats; flag lives in first 16B
  float* S     = ws + o; o += (size_t)total; o = (o + 3) & ~(size_t)3;
  float* X     = ws + o; o += (size_t)BB*LTOT*DM;
  float* LN    = ws + o; o += (size_t)BB*LTOT*DM;
  float* XZ    = ws + o; o += (size_t)BB*LTOT*2*DI;
  float* XC    = ws + o; o += (size_t)BB*LTOT*DI;
  float* DBL   = ws + o; o += (size_t)BB*LTOT*64;
  float* DELTA = ws + o; o += (size_t)BB*LTOT*DI;
  float* Yb    = ws + o; o += (size_t)BB*LTOT*DI;

  const float* xc    = S + a.prefix[0];
  const float* xt    = S + a.prefix[1];
  const float* Win   = S + a.prefix[2];
  const float* convw = S + a.prefix[3];
  const float* convb = S + a.prefix[4];
  const float* Wx    = S + a.prefix[5];
  const float* Wdt   = S + a.prefix[6];
  const float* bdt   = S + a.prefix[7];
  const float* Alog  = S + a.prefix[8];
  const float* Dv    = S + a.prefix[9];
  const float* Wout  = S + a.prefix[10];
  const float* lnw   = S + a.prefix[11];
  const float* lnb   = S + a.prefix[12];

  const int M = BB*LTOT;   // 2048
  k_detect<<<1, 256, 0, stream>>>((const unsigned short*)d_in[0], flag);
  k_convert<<<(total+255)/256, 256, 0, stream>>>(a, S, flag, total);
  k_init<<<(BB*LTOT*DM+255)/256, 256, 0, stream>>>(xc, xt, X);
  for (int l = 0; l < NL; ++l){
    k_ln<<<M, 256, 0, stream>>>(X, lnw + l*DM, lnb + l*DM, LN);
    k_gemm64<0><<<dim3(2*DI/64, M/64), 256, 0, stream>>>(LN, Win + (size_t)l*DM*2*DI, XZ, M, 2*DI, DM);
    k_conv<<<(M*DI+255)/256, 256, 0, stream>>>(XZ, convw + l*DI*DCONV, convb + l*DI, XC);
    k_dbl<<<M/4, 256, 0, stream>>>(XC, Wx + (size_t)l*DI*64, DBL);
    k_delta<<<dim3(DI/256, M), 256, 0, stream>>>(DBL, Wdt + (size_t)l*DTR*DI, bdt + l*DI, DELTA);
    k_scan<<<BB*DI/16, 256, 0, stream>>>(DELTA, XC, XZ, DBL, Alog + (size_t)l*DI*DS, Dv + l*DI, Yb);
    k_gemm64<1><<<dim3(DM/64, M/64), 256, 0, stream>>>(Yb, Wout + (size_t)l*DI*DM, X, M, DM, DI);
  }
  k_out<<<(BB*NTT*DM+255)/256, 256, 0, stream>>>(X, d_out, flag);
}

// Round 4
// 1029.620 us; speedup vs baseline: 1.8020x; 1.8020x over previous
//
#include <hip/hip_runtime.h>
#include <hip/hip_bf16.h>
#include <stdint.h>

#define NL 4
#define DM 512
#define DI 1024
#define DS 16
#define DTR 32
#define DCONV 4
#define BB 2
#define LTOT 1024
#define NCC 768
#define NTT 256
#define EPSV 1e-5f
#define NIN 13
#define NCH 16      // time chunks for parallel scan
#define TCH 64      // steps per chunk

typedef __hip_bfloat16 bf16;
__device__ __forceinline__ float b2f(bf16 v){ return __bfloat162float(v); }

struct ConvArgs { const void* src[NIN]; int prefix[NIN+1]; };

// ---------------- dtype detector: flag=1 if buffers are f32, 0 if bf16 ----------------
__global__ void k_detect(const unsigned short* __restrict__ u, int* __restrict__ flag){
  __shared__ int cnt[2];
  if (threadIdx.x < 2) cnt[threadIdx.x] = 0;
  __syncthreads();
  int h = 0, z = 0;
  for (int i = threadIdx.x; i < 4096; i += 256){
    unsigned short b = u[2*i];
    if (b == 0) z++;
    int e = (b >> 7) & 0xFF;
    if (e >= 142 && e != 0xFF) h++;
  }
  atomicAdd(&cnt[0], h);
  atomicAdd(&cnt[1], z);
  __syncthreads();
  if (threadIdx.x == 0) *flag = (cnt[0] > 64 || cnt[1] > 64) ? 1 : 0;
}

// ---------------- stage all inputs as f32 ----------------
__global__ __launch_bounds__(256) void k_convert(ConvArgs a, float* __restrict__ dst,
                                                 const int* __restrict__ flag, int total){
  int idx = blockIdx.x*256 + threadIdx.x;
  if (idx >= total) return;
  int bi = 0;
  #pragma unroll
  for (int i = 0; i < NIN-1; ++i) if (idx >= a.prefix[i+1]) bi = i+1;
  int off = idx - a.prefix[bi];
  float v = (*flag) ? ((const float*)a.src[bi])[off]
                    : b2f(((const bf16*)a.src[bi])[off]);
  dst[idx] = v;
}

// ---------------- init: concat xc|xt -> X (f32) ----------------
__global__ void k_init(const float* __restrict__ xc, const float* __restrict__ xt, float* __restrict__ X){
  int idx = blockIdx.x*256 + threadIdx.x;
  if (idx >= BB*LTOT*DM) return;
  int c = idx & (DM-1);
  int row = idx >> 9;
  int t = row & (LTOT-1);
  int b = row >> 10;
  X[idx] = (t < NCC) ? xc[(b*NCC + t)*DM + c] : xt[(b*NTT + (t-NCC))*DM + c];
}

// ---------------- layernorm over DM=512 ----------------
__global__ __launch_bounds__(256) void k_ln(const float* __restrict__ X, const float* __restrict__ w,
                                            const float* __restrict__ bia, float* __restrict__ LN){
  __shared__ float red[4];
  int row = blockIdx.x, tid = threadIdx.x;
  const float* xr = X + row*DM;
  float v0 = xr[tid], v1 = xr[tid+256];
  float s = v0 + v1;
  #pragma unroll
  for (int m = 32; m >= 1; m >>= 1) s += __shfl_xor(s, m, 64);
  if ((tid & 63) == 0) red[tid>>6] = s;
  __syncthreads();
  float mean = (red[0]+red[1]+red[2]+red[3]) * (1.0f/DM);
  __syncthreads();
  float d0 = v0-mean, d1 = v1-mean;
  float q = d0*d0 + d1*d1;
  #pragma unroll
  for (int m = 32; m >= 1; m >>= 1) q += __shfl_xor(q, m, 64);
  if ((tid & 63) == 0) red[tid>>6] = q;
  __syncthreads();
  float var = (red[0]+red[1]+red[2]+red[3]) * (1.0f/DM);
  float rs = rsqrtf(var + EPSV);
  LN[row*DM + tid]     = d0*rs*w[tid]     + bia[tid];
  LN[row*DM + tid+256] = d1*rs*w[tid+256] + bia[tid+256];
}

// ---------------- tiled f32 GEMM: C[M,N] (=|+=) A[M,K] @ W[K,N] ----------------
template<int ACC>
__global__ __launch_bounds__(256) void k_gemm64(const float* __restrict__ A, const float* __restrict__ W,
                                                float* __restrict__ C, int M, int N, int K){
  __shared__ __align__(16) float As[16][68];
  __shared__ __align__(16) float Ws[16][64];
  int tid = threadIdx.x;
  int tx = tid & 15, ty = tid >> 4;
  int n0 = blockIdx.x * 64, m0 = blockIdx.y * 64;
  int la_k = tid & 15, la_m = tid >> 4;
  int lw_n = tid & 63, lw_k = tid >> 6;
  float acc[4][4] = {};
  for (int k0 = 0; k0 < K; k0 += 16){
    #pragma unroll
    for (int e=0;e<4;e++)
      As[la_k][la_m + e*16] = A[(m0 + la_m + e*16)*K + k0 + la_k];
    #pragma unroll
    for (int e=0;e<4;e++)
      Ws[lw_k + e*4][lw_n] = W[(k0 + lw_k + e*4)*N + n0 + lw_n];
    __syncthreads();
    #pragma unroll
    for (int kk=0; kk<16; ++kk){
      float4 av = *(const float4*)&As[kk][ty*4];
      float4 bv = *(const float4*)&Ws[kk][tx*4];
      float a[4] = {av.x, av.y, av.z, av.w};
      float b[4] = {bv.x, bv.y, bv.z, bv.w};
      #pragma unroll
      for (int i=0;i<4;i++)
        #pragma unroll
        for (int j=0;j<4;j++)
          acc[i][j] = fmaf(a[i], b[j], acc[i][j]);
    }
    __syncthreads();
  }
  #pragma unroll
  for (int i=0;i<4;i++){
    int m = m0 + ty*4 + i;
    #pragma unroll
    for (int j=0;j<4;j++){
      int n = n0 + tx*4 + j;
      if (ACC) C[m*N+n] += acc[i][j];
      else     C[m*N+n]  = acc[i][j];
    }
  }
}

// ---------------- causal depthwise conv (D_CONV=4) + bias + SiLU ----------------
__global__ void k_conv(const float* __restrict__ XZ, const float* __restrict__ cw,
                       const float* __restrict__ cb, float* __restrict__ XC){
  int idx = blockIdx.x*256 + threadIdx.x;
  if (idx >= BB*LTOT*DI) return;
  int d = idx & (DI-1);
  int row = idx >> 10;
  int t = row & (LTOT-1);
  float acc = cb[d];
  #pragma unroll
  for (int k=0;k<DCONV;k++){
    int tt = t + k - (DCONV-1);
    if (tt >= 0) acc = fmaf(XZ[(row + k - (DCONV-1))*2*DI + d], cw[d*DCONV+k], acc);
  }
  acc = acc / (1.f + __expf(-acc));
  XC[idx] = acc;
}

// ---------------- DBL[M,64] = XC[M,1024] @ Wx[1024,64] ----------------
__global__ __launch_bounds__(256) void k_dbl(const float* __restrict__ XC, const float* __restrict__ Wx,
                                             float* __restrict__ DBL){
  __shared__ float sx[4][DI];
  int tid = threadIdx.x;
  int m0 = blockIdx.x * 4;
  #pragma unroll
  for (int e = 0; e < 16; ++e){
    int off = e*256 + tid;
    sx[off >> 10][off & (DI-1)] = XC[(m0 + (off>>10))*DI + (off & (DI-1))];
  }
  __syncthreads();
  int r = tid >> 6, c = tid & 63;
  float acc = 0.f;
  #pragma unroll 8
  for (int k=0;k<DI;k++) acc = fmaf(sx[r][k], Wx[k*64 + c], acc);
  DBL[(m0+r)*64 + c] = acc;
}

// ---------------- DELTA[M,1024] = softplus(DBL[:, :32] @ Wdt[32,1024] + b_dt) ----------------
__global__ __launch_bounds__(256) void k_delta(const float* __restrict__ DBL, const float* __restrict__ Wdt,
                                               const float* __restrict__ bdt, float* __restrict__ DELTA){
  __shared__ float sdt[DTR];
  int m = blockIdx.y;
  int n0 = blockIdx.x*256;
  int tid = threadIdx.x;
  if (tid < DTR) sdt[tid] = DBL[m*64 + tid];
  __syncthreads();
  int n = n0 + tid;
  float acc = bdt[n];
  #pragma unroll
  for (int k=0;k<DTR;k++) acc = fmaf(sdt[k], Wdt[k*DI + n], acc);
  DELTA[m*DI + n] = (acc > 20.f) ? acc : log1pf(__expf(acc));
}

// ================= chunked parallel scan =================
// Recurrence h_t = a_t h_{t-1} + b_t. Per chunk c: local scan with h=0 gives q, P=prod(a).
// h_t = q_t + P_t * h_in.  Phase A: (P,S=q_end) per chunk. Phase B: propagate h_in.
// Phase C: re-scan from h_in, emit y.

// Phase A: 2048 blocks = (b, dgroup, chunk); 256 thr = 16 ch x 16 n.
__global__ __launch_bounds__(256) void k_scanA(const float* __restrict__ DELTA, const float* __restrict__ XC,
                                               const float* __restrict__ DBL, const float* __restrict__ Alog,
                                               float* __restrict__ Pb, float* __restrict__ Sb){
  __shared__ __align__(16) float s_del[16][68], s_x[16][68], s_B[16][68];
  int tid = threadIdx.x;
  int c  = blockIdx.x & (NCH-1);
  int dg = (blockIdx.x >> 4) & 63;
  int b  = blockIdx.x >> 10;
  int d0 = dg*16, t0 = c*TCH;
  int j = tid & 15, i0 = tid >> 4;
  #pragma unroll
  for (int e=0;e<4;e++){
    int i = i0 + e*16;
    int row = b*LTOT + t0 + i;
    s_del[j][i] = DELTA[row*DI + d0 + j];
    s_x[j][i]   = XC[row*DI + d0 + j];
    s_B[j][i]   = DBL[row*64 + 32 + j];
  }
  __syncthreads();
  int ch = tid >> 4, n = tid & 15;
  float An = -__expf(Alog[(d0+ch)*DS + n]);
  float h = 0.f, P = 1.f;
  for (int t=0;t<TCH;t+=4){
    float4 d4 = *(const float4*)&s_del[ch][t];
    float4 x4 = *(const float4*)&s_x[ch][t];
    float4 B4 = *(const float4*)&s_B[n][t];
    float a0 = __expf(d4.x*An), a1 = __expf(d4.y*An);
    float a2 = __expf(d4.z*An), a3 = __expf(d4.w*An);
    h = fmaf(a0, h, d4.x*B4.x*x4.x);
    h = fmaf(a1, h, d4.y*B4.y*x4.y);
    h = fmaf(a2, h, d4.z*B4.z*x4.z);
    h = fmaf(a3, h, d4.w*B4.w*x4.w);
    P *= (a0*a1)*(a2*a3);
  }
  int idx = (((b*DI) + d0 + ch)*NCH + c)*DS + n;
  Pb[idx] = P; Sb[idx] = h;
}

// Phase B: propagate chunk-entry states. 32768 threads, one per (b,d,n).
__global__ void k_scanB(const float* __restrict__ Pb, const float* __restrict__ Sb, float* __restrict__ Hin){
  int idx = blockIdx.x*256 + threadIdx.x;
  if (idx >= BB*DI*DS) return;
  int n = idx & 15;
  int d = (idx >> 4) & (DI-1);
  int b = idx >> 14;
  int base = ((b*DI + d)*NCH)*DS + n;
  float h = 0.f;
  #pragma unroll
  for (int c=0;c<NCH;c++){
    Hin[base + c*DS] = h;
    h = fmaf(Pb[base + c*DS], h, Sb[base + c*DS]);
  }
}

// Phase C: re-scan from Hin with fused epilogue y = (sum_n h C + x D) * silu(z).
__global__ __launch_bounds__(256) void k_scanC(const float* __restrict__ DELTA, const float* __restrict__ XC,
                                               const float* __restrict__ XZ, const float* __restrict__ DBL,
                                               const float* __restrict__ Alog, const float* __restrict__ Dv,
                                               const float* __restrict__ Hin, float* __restrict__ Y){
  __shared__ __align__(16) float s_del[16][68], s_x[16][68], s_B[16][68], s_C[16][68], s_z[16][68], s_y[16][68];
  int tid = threadIdx.x;
  int c  = blockIdx.x & (NCH-1);
  int dg = (blockIdx.x >> 4) & 63;
  int b  = blockIdx.x >> 10;
  int d0 = dg*16, t0 = c*TCH;
  int j = tid & 15, i0 = tid >> 4;
  #pragma unroll
  for (int e=0;e<4;e++){
    int i = i0 + e*16;
    int row = b*LTOT + t0 + i;
    s_del[j][i] = DELTA[row*DI + d0 + j];
    s_x[j][i]   = XC[row*DI + d0 + j];
    s_z[j][i]   = XZ[row*2*DI + DI + d0 + j];
    s_B[j][i]   = DBL[row*64 + 32 + j];
    s_C[j][i]   = DBL[row*64 + 48 + j];
  }
  __syncthreads();
  int ch = tid >> 4, n = tid & 15;
  int d  = d0 + ch;
  float An = -__expf(Alog[d*DS + n]);
  float Dd = Dv[d];
  float h = Hin[(((b*DI) + d)*NCH + c)*DS + n];
  for (int t=0;t<TCH;t+=4){
    float4 d4 = *(const float4*)&s_del[ch][t];
    float4 x4 = *(const float4*)&s_x[ch][t];
    float4 B4 = *(const float4*)&s_B[n][t];
    float4 C4 = *(const float4*)&s_C[n][t];
    float a0 = __expf(d4.x*An), a1 = __expf(d4.y*An);
    float a2 = __expf(d4.z*An), a3 = __expf(d4.w*An);
    h = fmaf(a0, h, d4.x*B4.x*x4.x); float p0 = h*C4.x;
    h = fmaf(a1, h, d4.y*B4.y*x4.y); float p1 = h*C4.y;
    h = fmaf(a2, h, d4.z*B4.z*x4.z); float p2 = h*C4.z;
    h = fmaf(a3, h, d4.w*B4.w*x4.w); float p3 = h*C4.w;
    #pragma unroll
    for (int m = 8; m >= 1; m >>= 1){
      p0 += __shfl_xor(p0, m, 16);
      p1 += __shfl_xor(p1, m, 16);
      p2 += __shfl_xor(p2, m, 16);
      p3 += __shfl_xor(p3, m, 16);
    }
    if (n == 0){
      float4 z4 = *(const float4*)&s_z[ch][t];
      s_y[ch][t]   = (p0 + x4.x*Dd) * (z4.x / (1.f + __expf(-z4.x)));
      s_y[ch][t+1] = (p1 + x4.y*Dd) * (z4.y / (1.f + __expf(-z4.y)));
      s_y[ch][t+2] = (p2 + x4.z*Dd) * (z4.z / (1.f + __expf(-z4.z)));
      s_y[ch][t+3] = (p3 + x4.w*Dd) * (z4.w / (1.f + __expf(-z4.w)));
    }
  }
  __syncthreads();
  #pragma unroll
  for (int e=0;e<4;e++){
    int i = i0 + e*16;
    int row = b*LTOT + t0 + i;
    Y[row*DI + d0 + j] = s_y[j][i];
  }
}

// ---------------- final slice + dtype-dispatched store ----------------
__global__ void k_out(const float* __restrict__ X, void* __restrict__ out, const int* __restrict__ flag){
  int idx = blockIdx.x*256 + threadIdx.x;
  if (idx >= BB*NTT*DM) return;
  int c = idx & (DM-1);
  int r = idx >> 9;
  int t = r & (NTT-1);
  int b = r >> 8;
  float v = X[(b*LTOT + NCC + t)*DM + c];
  if (*flag) ((float*)out)[idx] = v;
  else       ((bf16*)out)[idx] = __float2bfloat16(v);
}

extern "C" void kernel_launch(void* const* d_in, const int* in_sizes, int n_in,
                              void* d_out, int out_size, void* d_ws, size_t ws_size,
                              hipStream_t stream){
  ConvArgs a;
  int total = 0;
  for (int i = 0; i < NIN; ++i){ a.src[i] = d_in[i]; a.prefix[i] = total; total += in_sizes[i]; }
  a.prefix[NIN] = total;

  float* ws = (float*)d_ws;
  int* flag = (int*)d_ws;
  size_t o = 16;
  float* S     = ws + o; o += (size_t)total; o = (o + 3) & ~(size_t)3;
  float* X     = ws + o; o += (size_t)BB*LTOT*DM;
  float* LN    = ws + o; o += (size_t)BB*LTOT*DM;
  float* XZ    = ws + o; o += (size_t)BB*LTOT*2*DI;
  float* XC    = ws + o; o += (size_t)BB*LTOT*DI;
  float* DBL   = ws + o; o += (size_t)BB*LTOT*64;
  float* DELTA = ws + o; o += (size_t)BB*LTOT*DI;
  float* Yb    = ws + o; o += (size_t)BB*LTOT*DI;
  float* Pb    = ws + o; o += (size_t)BB*DI*NCH*DS;
  float* Sb    = ws + o; o += (size_t)BB*DI*NCH*DS;
  float* Hin   = ws + o; o += (size_t)BB*DI*NCH*DS;

  const float* xc    = S + a.prefix[0];
  const float* xt    = S + a.prefix[1];
  const float* Win   = S + a.prefix[2];
  const float* convw = S + a.prefix[3];
  const float* convb = S + a.prefix[4];
  const float* Wx    = S + a.prefix[5];
  const float* Wdt   = S + a.prefix[6];
  const float* bdt   = S + a.prefix[7];
  const float* Alog  = S + a.prefix[8];
  const float* Dv    = S + a.prefix[9];
  const float* Wout  = S + a.prefix[10];
  const float* lnw   = S + a.prefix[11];
  const float* lnb   = S + a.prefix[12];

  const int M = BB*LTOT;   // 2048
  k_detect<<<1, 256, 0, stream>>>((const unsigned short*)d_in[0], flag);
  k_convert<<<(total+255)/256, 256, 0, stream>>>(a, S, flag, total);
  k_init<<<(BB*LTOT*DM+255)/256, 256, 0, stream>>>(xc, xt, X);
  for (int l = 0; l < NL; ++l){
    k_ln<<<M, 256, 0, stream>>>(X, lnw + l*DM, lnb + l*DM, LN);
    k_gemm64<0><<<dim3(2*DI/64, M/64), 256, 0, stream>>>(LN, Win + (size_t)l*DM*2*DI, XZ, M, 2*DI, DM);
    k_conv<<<(M*DI+255)/256, 256, 0, stream>>>(XZ, convw + l*DI*DCONV, convb + l*DI, XC);
    k_dbl<<<M/4, 256, 0, stream>>>(XC, Wx + (size_t)l*DI*64, DBL);
    k_delta<<<dim3(DI/256, M), 256, 0, stream>>>(DBL, Wdt + (size_t)l*DTR*DI, bdt + l*DI, DELTA);
    k_scanA<<<BB*64*NCH, 256, 0, stream>>>(DELTA, XC, DBL, Alog + (size_t)l*DI*DS, Pb, Sb);
    k_scanB<<<(BB*DI*DS+255)/256, 256, 0, stream>>>(Pb, Sb, Hin);
    k_scanC<<<BB*64*NCH, 256, 0, stream>>>(DELTA, XC, XZ, DBL, Alog + (size_t)l*DI*DS, Dv + l*DI, Hin, Yb);
    k_gemm64<1><<<dim3(DM/64, M/64), 256, 0, stream>>>(Yb, Wout + (size_t)l*DI*DM, X, M, DM, DI);
  }
  k_out<<<(BB*NTT*DM+255)/256, 256, 0, stream>>>(X, d_out, flag);
}

// Round 5
// 670.637 us; speedup vs baseline: 2.7666x; 1.5353x over previous
//
#include <hip/hip_runtime.h>
#include <hip/hip_bf16.h>
#include <stdint.h>

#define NL 4
#define DM 512
#define DI 1024
#define DS 16
#define DTR 32
#define DCONV 4
#define BB 2
#define LTOT 1024
#define NCC 768
#define NTT 256
#define EPSV 1e-5f
#define NIN 13
#define NCH 16
#define TCH 64

typedef __hip_bfloat16 bf16;
typedef __attribute__((ext_vector_type(8))) short bf16v8;
typedef __attribute__((ext_vector_type(4))) float f32x4;
__device__ __forceinline__ float b2f(bf16 v){ return __bfloat162float(v); }

struct ConvArgs { const void* src[NIN]; int prefix[NIN+1]; };

// ---------------- dtype detector ----------------
__global__ void k_detect(const unsigned short* __restrict__ u, int* __restrict__ flag){
  __shared__ int cnt[2];
  if (threadIdx.x < 2) cnt[threadIdx.x] = 0;
  __syncthreads();
  int h = 0, z = 0;
  for (int i = threadIdx.x; i < 4096; i += 256){
    unsigned short b = u[2*i];
    if (b == 0) z++;
    int e = (b >> 7) & 0xFF;
    if (e >= 142 && e != 0xFF) h++;
  }
  atomicAdd(&cnt[0], h);
  atomicAdd(&cnt[1], z);
  __syncthreads();
  if (threadIdx.x == 0) *flag = (cnt[0] > 64 || cnt[1] > 64) ? 1 : 0;
}

// ---------------- stage all inputs as f32 ----------------
__global__ __launch_bounds__(256) void k_convert(ConvArgs a, float* __restrict__ dst,
                                                 const int* __restrict__ flag, int total){
  int idx = blockIdx.x*256 + threadIdx.x;
  if (idx >= total) return;
  int bi = 0;
  #pragma unroll
  for (int i = 0; i < NIN-1; ++i) if (idx >= a.prefix[i+1]) bi = i+1;
  int off = idx - a.prefix[bi];
  float v = (*flag) ? ((const float*)a.src[bi])[off]
                    : b2f(((const bf16*)a.src[bi])[off]);
  dst[idx] = v;
}

// ---------------- weight transpose + bf16 cast: W[K,N] f32 -> WT[N,K] bf16 ----------------
__global__ __launch_bounds__(256) void k_transp(const float* __restrict__ W, bf16* __restrict__ WT,
                                                int K, int N){
  __shared__ float tile[32][33];
  int l = blockIdx.z;
  const float* Wl = W + (size_t)l*K*N;
  bf16* WTl = WT + (size_t)l*K*N;
  int n0 = blockIdx.x*32, k0 = blockIdx.y*32;
  int tx = threadIdx.x & 31, ty = threadIdx.x >> 5;
  #pragma unroll
  for (int e=0;e<4;e++)
    tile[ty+8*e][tx] = Wl[(size_t)(k0+ty+8*e)*N + n0+tx];
  __syncthreads();
  #pragma unroll
  for (int e=0;e<4;e++)
    WTl[(size_t)(n0+ty+8*e)*K + k0+tx] = __float2bfloat16(tile[tx][ty+8*e]);
}

// ---------------- init: concat xc|xt -> X ----------------
__global__ void k_init(const float* __restrict__ xc, const float* __restrict__ xt, float* __restrict__ X){
  int idx = blockIdx.x*256 + threadIdx.x;
  if (idx >= BB*LTOT*DM) return;
  int c = idx & (DM-1);
  int row = idx >> 9;
  int t = row & (LTOT-1);
  int b = row >> 10;
  X[idx] = (t < NCC) ? xc[(b*NCC + t)*DM + c] : xt[(b*NTT + (t-NCC))*DM + c];
}

// ---------------- layernorm -> bf16 (GEMM A-operand) ----------------
__global__ __launch_bounds__(256) void k_ln(const float* __restrict__ X, const float* __restrict__ w,
                                            const float* __restrict__ bia, bf16* __restrict__ LNb){
  __shared__ float red[4];
  int row = blockIdx.x, tid = threadIdx.x;
  const float* xr = X + row*DM;
  float v0 = xr[tid], v1 = xr[tid+256];
  float s = v0 + v1;
  #pragma unroll
  for (int m = 32; m >= 1; m >>= 1) s += __shfl_xor(s, m, 64);
  if ((tid & 63) == 0) red[tid>>6] = s;
  __syncthreads();
  float mean = (red[0]+red[1]+red[2]+red[3]) * (1.0f/DM);
  __syncthreads();
  float d0 = v0-mean, d1 = v1-mean;
  float q = d0*d0 + d1*d1;
  #pragma unroll
  for (int m = 32; m >= 1; m >>= 1) q += __shfl_xor(q, m, 64);
  if ((tid & 63) == 0) red[tid>>6] = q;
  __syncthreads();
  float var = (red[0]+red[1]+red[2]+red[3]) * (1.0f/DM);
  float rs = rsqrtf(var + EPSV);
  LNb[row*DM + tid]     = __float2bfloat16(d0*rs*w[tid]     + bia[tid]);
  LNb[row*DM + tid+256] = __float2bfloat16(d1*rs*w[tid+256] + bia[tid+256]);
}

// ---------------- MFMA bf16 GEMM: C[M,N] (=|+=) A[M,K]bf16 @ Bt[N,K]bf16 ----------------
template<int BM,int BN,int ACC>
__global__ __launch_bounds__(256) void k_mfma(const bf16* __restrict__ A, const bf16* __restrict__ Bt,
                                              float* __restrict__ C, int M, int N, int K){
  constexpr int SA = 72;   // LDS row stride (elems): 144B = 9*16B -> aligned b128, conflict-free
  __shared__ __align__(16) bf16 As[BM*SA];
  __shared__ __align__(16) bf16 Bs[BN*SA];
  constexpr int WM = BM/2, WN = BN/2;
  constexpr int FM = WM/16, FN = WN/16;
  int tid = threadIdx.x;
  int lane = tid & 63, w = tid >> 6;
  int wr = w >> 1, wc = w & 1;
  int m0 = blockIdx.y*BM, n0 = blockIdx.x*BN;
  f32x4 acc[FM][FN] = {};
  int srow = tid >> 3, sslot = tid & 7;
  for (int k0 = 0; k0 < K; k0 += 64){
    #pragma unroll
    for (int g = 0; g < BM/32; ++g){
      int row = g*32 + srow;
      uint4 v = *(const uint4*)&A[(size_t)(m0+row)*K + k0 + sslot*8];
      *(uint4*)&As[row*SA + sslot*8] = v;
    }
    #pragma unroll
    for (int g = 0; g < BN/32; ++g){
      int row = g*32 + srow;
      uint4 v = *(const uint4*)&Bt[(size_t)(n0+row)*K + k0 + sslot*8];
      *(uint4*)&Bs[row*SA + sslot*8] = v;
    }
    __syncthreads();
    #pragma unroll
    for (int kk = 0; kk < 2; ++kk){
      bf16v8 af[FM], bg[FN];
      #pragma unroll
      for (int i=0;i<FM;i++)
        af[i] = *(const bf16v8*)&As[(wr*WM + i*16 + (lane&15))*SA + (kk*4 + (lane>>4))*8];
      #pragma unroll
      for (int j=0;j<FN;j++)
        bg[j] = *(const bf16v8*)&Bs[(wc*WN + j*16 + (lane&15))*SA + (kk*4 + (lane>>4))*8];
      #pragma unroll
      for (int i=0;i<FM;i++)
        #pragma unroll
        for (int j=0;j<FN;j++)
          acc[i][j] = __builtin_amdgcn_mfma_f32_16x16x32_bf16(af[i], bg[j], acc[i][j], 0, 0, 0);
    }
    __syncthreads();
  }
  int crow = (lane>>4)*4, ccol = lane&15;
  #pragma unroll
  for (int i=0;i<FM;i++){
    #pragma unroll
    for (int j=0;j<FN;j++){
      int mbase = m0 + wr*WM + i*16 + crow;
      int n = n0 + wc*WN + j*16 + ccol;
      #pragma unroll
      for (int r=0;r<4;r++){
        if (ACC) C[(size_t)(mbase+r)*N + n] += acc[i][j][r];
        else     C[(size_t)(mbase+r)*N + n]  = acc[i][j][r];
      }
    }
  }
}

// ---------------- causal depthwise conv + bias + SiLU ----------------
__global__ void k_conv(const float* __restrict__ XZ, const float* __restrict__ cw,
                       const float* __restrict__ cb, float* __restrict__ XC){
  int idx = blockIdx.x*256 + threadIdx.x;
  if (idx >= BB*LTOT*DI) return;
  int d = idx & (DI-1);
  int row = idx >> 10;
  int t = row & (LTOT-1);
  float acc = cb[d];
  #pragma unroll
  for (int k=0;k<DCONV;k++){
    int tt = t + k - (DCONV-1);
    if (tt >= 0) acc = fmaf(XZ[(row + k - (DCONV-1))*2*DI + d], cw[d*DCONV+k], acc);
  }
  acc = acc / (1.f + __expf(-acc));
  XC[idx] = acc;
}

// ---------------- DBL[M,64] = XC[M,1024] @ Wx[1024,64] ----------------
__global__ __launch_bounds__(256) void k_dbl(const float* __restrict__ XC, const float* __restrict__ Wx,
                                             float* __restrict__ DBL){
  __shared__ float sx[4][DI];
  int tid = threadIdx.x;
  int m0 = blockIdx.x * 4;
  #pragma unroll
  for (int e = 0; e < 16; ++e){
    int off = e*256 + tid;
    sx[off >> 10][off & (DI-1)] = XC[(m0 + (off>>10))*DI + (off & (DI-1))];
  }
  __syncthreads();
  int r = tid >> 6, c = tid & 63;
  float acc = 0.f;
  #pragma unroll 8
  for (int k=0;k<DI;k++) acc = fmaf(sx[r][k], Wx[k*64 + c], acc);
  DBL[(m0+r)*64 + c] = acc;
}

// ---------------- DELTA = softplus(DBL[:, :32] @ Wdt + b_dt) ----------------
__global__ __launch_bounds__(256) void k_delta(const float* __restrict__ DBL, const float* __restrict__ Wdt,
                                               const float* __restrict__ bdt, float* __restrict__ DELTA){
  __shared__ float sdt[DTR];
  int m = blockIdx.y;
  int n0 = blockIdx.x*256;
  int tid = threadIdx.x;
  if (tid < DTR) sdt[tid] = DBL[m*64 + tid];
  __syncthreads();
  int n = n0 + tid;
  float acc = bdt[n];
  #pragma unroll
  for (int k=0;k<DTR;k++) acc = fmaf(sdt[k], Wdt[k*DI + n], acc);
  DELTA[m*DI + n] = (acc > 20.f) ? acc : log1pf(__expf(acc));
}

// ================= chunked parallel scan =================
__global__ __launch_bounds__(256) void k_scanA(const float* __restrict__ DELTA, const float* __restrict__ XC,
                                               const float* __restrict__ DBL, const float* __restrict__ Alog,
                                               float* __restrict__ Pb, float* __restrict__ Sb){
  __shared__ __align__(16) float s_del[16][68], s_x[16][68], s_B[16][68];
  int tid = threadIdx.x;
  int c  = blockIdx.x & (NCH-1);
  int dg = (blockIdx.x >> 4) & 63;
  int b  = blockIdx.x >> 10;
  int d0 = dg*16, t0 = c*TCH;
  int j = tid & 15, i0 = tid >> 4;
  #pragma unroll
  for (int e=0;e<4;e++){
    int i = i0 + e*16;
    int row = b*LTOT + t0 + i;
    s_del[j][i] = DELTA[row*DI + d0 + j];
    s_x[j][i]   = XC[row*DI + d0 + j];
    s_B[j][i]   = DBL[row*64 + 32 + j];
  }
  __syncthreads();
  int ch = tid >> 4, n = tid & 15;
  float An = -__expf(Alog[(d0+ch)*DS + n]);
  float h = 0.f, P = 1.f;
  for (int t=0;t<TCH;t+=4){
    float4 d4 = *(const float4*)&s_del[ch][t];
    float4 x4 = *(const float4*)&s_x[ch][t];
    float4 B4 = *(const float4*)&s_B[n][t];
    float a0 = __expf(d4.x*An), a1 = __expf(d4.y*An);
    float a2 = __expf(d4.z*An), a3 = __expf(d4.w*An);
    h = fmaf(a0, h, d4.x*B4.x*x4.x);
    h = fmaf(a1, h, d4.y*B4.y*x4.y);
    h = fmaf(a2, h, d4.z*B4.z*x4.z);
    h = fmaf(a3, h, d4.w*B4.w*x4.w);
    P *= (a0*a1)*(a2*a3);
  }
  int idx = (((b*DI) + d0 + ch)*NCH + c)*DS + n;
  Pb[idx] = P; Sb[idx] = h;
}

__global__ void k_scanB(const float* __restrict__ Pb, const float* __restrict__ Sb, float* __restrict__ Hin){
  int idx = blockIdx.x*256 + threadIdx.x;
  if (idx >= BB*DI*DS) return;
  int n = idx & 15;
  int d = (idx >> 4) & (DI-1);
  int b = idx >> 14;
  int base = ((b*DI + d)*NCH)*DS + n;
  float h = 0.f;
  #pragma unroll
  for (int c=0;c<NCH;c++){
    Hin[base + c*DS] = h;
    h = fmaf(Pb[base + c*DS], h, Sb[base + c*DS]);
  }
}

// Phase C: re-scan + fused epilogue -> Y bf16 (Wout GEMM A-operand)
__global__ __launch_bounds__(256) void k_scanC(const float* __restrict__ DELTA, const float* __restrict__ XC,
                                               const float* __restrict__ XZ, const float* __restrict__ DBL,
                                               const float* __restrict__ Alog, const float* __restrict__ Dv,
                                               const float* __restrict__ Hin, bf16* __restrict__ Y){
  __shared__ __align__(16) float s_del[16][68], s_x[16][68], s_B[16][68], s_C[16][68], s_z[16][68], s_y[16][68];
  int tid = threadIdx.x;
  int c  = blockIdx.x & (NCH-1);
  int dg = (blockIdx.x >> 4) & 63;
  int b  = blockIdx.x >> 10;
  int d0 = dg*16, t0 = c*TCH;
  int j = tid & 15, i0 = tid >> 4;
  #pragma unroll
  for (int e=0;e<4;e++){
    int i = i0 + e*16;
    int row = b*LTOT + t0 + i;
    s_del[j][i] = DELTA[row*DI + d0 + j];
    s_x[j][i]   = XC[row*DI + d0 + j];
    s_z[j][i]   = XZ[row*2*DI + DI + d0 + j];
    s_B[j][i]   = DBL[row*64 + 32 + j];
    s_C[j][i]   = DBL[row*64 + 48 + j];
  }
  __syncthreads();
  int ch = tid >> 4, n = tid & 15;
  int d  = d0 + ch;
  float An = -__expf(Alog[d*DS + n]);
  float Dd = Dv[d];
  float h = Hin[(((b*DI) + d)*NCH + c)*DS + n];
  for (int t=0;t<TCH;t+=4){
    float4 d4 = *(const float4*)&s_del[ch][t];
    float4 x4 = *(const float4*)&s_x[ch][t];
    float4 B4 = *(const float4*)&s_B[n][t];
    float4 C4 = *(const float4*)&s_C[n][t];
    float a0 = __expf(d4.x*An), a1 = __expf(d4.y*An);
    float a2 = __expf(d4.z*An), a3 = __expf(d4.w*An);
    h = fmaf(a0, h, d4.x*B4.x*x4.x); float p0 = h*C4.x;
    h = fmaf(a1, h, d4.y*B4.y*x4.y); float p1 = h*C4.y;
    h = fmaf(a2, h, d4.z*B4.z*x4.z); float p2 = h*C4.z;
    h = fmaf(a3, h, d4.w*B4.w*x4.w); float p3 = h*C4.w;
    #pragma unroll
    for (int m = 8; m >= 1; m >>= 1){
      p0 += __shfl_xor(p0, m, 16);
      p1 += __shfl_xor(p1, m, 16);
      p2 += __shfl_xor(p2, m, 16);
      p3 += __shfl_xor(p3, m, 16);
    }
    if (n == 0){
      float4 z4 = *(const float4*)&s_z[ch][t];
      s_y[ch][t]   = (p0 + x4.x*Dd) * (z4.x / (1.f + __expf(-z4.x)));
      s_y[ch][t+1] = (p1 + x4.y*Dd) * (z4.y / (1.f + __expf(-z4.y)));
      s_y[ch][t+2] = (p2 + x4.z*Dd) * (z4.z / (1.f + __expf(-z4.z)));
      s_y[ch][t+3] = (p3 + x4.w*Dd) * (z4.w / (1.f + __expf(-z4.w)));
    }
  }
  __syncthreads();
  #pragma unroll
  for (int e=0;e<4;e++){
    int i = i0 + e*16;
    int row = b*LTOT + t0 + i;
    Y[row*DI + d0 + j] = __float2bfloat16(s_y[j][i]);
  }
}

// ---------------- final slice + dtype-dispatched store ----------------
__global__ void k_out(const float* __restrict__ X, void* __restrict__ out, const int* __restrict__ flag){
  int idx = blockIdx.x*256 + threadIdx.x;
  if (idx >= BB*NTT*DM) return;
  int c = idx & (DM-1);
  int r = idx >> 9;
  int t = r & (NTT-1);
  int b = r >> 8;
  float v = X[(b*LTOT + NCC + t)*DM + c];
  if (*flag) ((float*)out)[idx] = v;
  else       ((bf16*)out)[idx] = __float2bfloat16(v);
}

extern "C" void kernel_launch(void* const* d_in, const int* in_sizes, int n_in,
                              void* d_out, int out_size, void* d_ws, size_t ws_size,
                              hipStream_t stream){
  ConvArgs a;
  int total = 0;
  for (int i = 0; i < NIN; ++i){ a.src[i] = d_in[i]; a.prefix[i] = total; total += in_sizes[i]; }
  a.prefix[NIN] = total;

  float* ws = (float*)d_ws;
  int* flag = (int*)d_ws;
  size_t o = 16;
  float* S     = ws + o; o += (size_t)total;        o = (o + 3) & ~(size_t)3;
  float* X     = ws + o; o += (size_t)BB*LTOT*DM;
  float* XZ    = ws + o; o += (size_t)BB*LTOT*2*DI;
  float* XC    = ws + o; o += (size_t)BB*LTOT*DI;
  float* DBL   = ws + o; o += (size_t)BB*LTOT*64;
  float* DELTA = ws + o; o += (size_t)BB*LTOT*DI;
  float* Pb    = ws + o; o += (size_t)BB*DI*NCH*DS;
  float* Sb    = ws + o; o += (size_t)BB*DI*NCH*DS;
  float* Hin   = ws + o; o += (size_t)BB*DI*NCH*DS;
  bf16*  LNb   = (bf16*)(ws + o); o += (size_t)BB*LTOT*DM/2;
  bf16*  Yb    = (bf16*)(ws + o); o += (size_t)BB*LTOT*DI/2;
  bf16*  WinT  = (bf16*)(ws + o); o += (size_t)NL*DM*2*DI/2;
  bf16*  WoutT = (bf16*)(ws + o); o += (size_t)NL*DI*DM/2;

  const float* xc    = S + a.prefix[0];
  const float* xt    = S + a.prefix[1];
  const float* Win   = S + a.prefix[2];
  const float* convw = S + a.prefix[3];
  const float* convb = S + a.prefix[4];
  const float* Wx    = S + a.prefix[5];
  const float* Wdt   = S + a.prefix[6];
  const float* bdt   = S + a.prefix[7];
  const float* Alog  = S + a.prefix[8];
  const float* Dv    = S + a.prefix[9];
  const float* Wout  = S + a.prefix[10];
  const float* lnw   = S + a.prefix[11];
  const float* lnb   = S + a.prefix[12];

  const int M = BB*LTOT;   // 2048
  k_detect<<<1, 256, 0, stream>>>((const unsigned short*)d_in[0], flag);
  k_convert<<<(total+255)/256, 256, 0, stream>>>(a, S, flag, total);
  k_transp<<<dim3(2*DI/32, DM/32, NL), 256, 0, stream>>>(Win, WinT, DM, 2*DI);
  k_transp<<<dim3(DM/32, DI/32, NL), 256, 0, stream>>>(Wout, WoutT, DI, DM);
  k_init<<<(BB*LTOT*DM+255)/256, 256, 0, stream>>>(xc, xt, X);
  for (int l = 0; l < NL; ++l){
    k_ln<<<M, 256, 0, stream>>>(X, lnw + l*DM, lnb + l*DM, LNb);
    k_mfma<128,128,0><<<dim3(2*DI/128, M/128), 256, 0, stream>>>(LNb, WinT + (size_t)l*DM*2*DI, XZ, M, 2*DI, DM);
    k_conv<<<(M*DI+255)/256, 256, 0, stream>>>(XZ, convw + l*DI*DCONV, convb + l*DI, XC);
    k_dbl<<<M/4, 256, 0, stream>>>(XC, Wx + (size_t)l*DI*64, DBL);
    k_delta<<<dim3(DI/256, M), 256, 0, stream>>>(DBL, Wdt + (size_t)l*DTR*DI, bdt + l*DI, DELTA);
    k_scanA<<<BB*64*NCH, 256, 0, stream>>>(DELTA, XC, DBL, Alog + (size_t)l*DI*DS, Pb, Sb);
    k_scanB<<<(BB*DI*DS+255)/256, 256, 0, stream>>>(Pb, Sb, Hin);
    k_scanC<<<BB*64*NCH, 256, 0, stream>>>(DELTA, XC, XZ, DBL, Alog + (size_t)l*DI*DS, Dv + l*DI, Hin, Yb);
    k_mfma<64,128,1><<<dim3(DM/128, M/64), 256, 0, stream>>>(Yb, WoutT + (size_t)l*DI*DM, X, M, DM, DI);
  }
  k_out<<<(BB*NTT*DM+255)/256, 256, 0, stream>>>(X, d_out, flag);
}